// Round 2
// baseline (63.104 us; speedup 1.0000x reference)
//
#include <hip/hip_runtime.h>

#define B_ 8
#define N_ 256
#define D_ 512
#define TI 4   // query rows per block

// ---------- Kernel 0: transpose k[b][j][d] -> kT[b][d][j] ----------
// 32x32 tiles, block (32,8), grid (D_/32, N_/32, B_)
__global__ __launch_bounds__(256)
void transpose_k(const float* __restrict__ k, float* __restrict__ kT)
{
    __shared__ float tile[32][33];
    const int dt = blockIdx.x * 32;
    const int jt = blockIdx.y * 32;
    const int b  = blockIdx.z;
    const int tx = threadIdx.x;   // 0..31
    const int ty = threadIdx.y;   // 0..7

    const float* __restrict__ src = k  + ((size_t)b * N_) * D_;
    float* __restrict__       dst = kT + ((size_t)b * D_) * N_;

    #pragma unroll
    for (int r = 0; r < 4; ++r) {
        const int jj = ty * 4 + r;
        tile[jj][tx] = src[(size_t)(jt + jj) * D_ + dt + tx];
    }
    __syncthreads();
    #pragma unroll
    for (int r = 0; r < 4; ++r) {
        const int dd = ty * 4 + r;
        dst[(size_t)(dt + dd) * N_ + jt + tx] = tile[tx][dd];
    }
}

// ---------- Main fused kernel (coalesced k via kT) ----------
// grid = B_ * (N_/TI) = 512 blocks, 256 threads (4 waves)
__global__ __launch_bounds__(256, 2)
void manh_attn_kernel(const float* __restrict__ q,
                      const float* __restrict__ kT,
                      const float* __restrict__ v,
                      float* __restrict__ out)
{
    __shared__ float s_mat[TI][N_];

    const int t   = threadIdx.x;
    const int bid = blockIdx.x;
    const int b   = bid >> 6;
    const int i0  = (bid & 63) * TI;

    // ---------------- Phase A: L1 distance, column j = t ----------------
    // kT[b][d][j]: lane-consecutive j -> fully coalesced (256B/wave-load).
    // q rows are block-uniform -> scalar (s_load) pipe.
    const float* __restrict__ kcol  = kT + ((size_t)b * D_) * N_ + t;
    const float* __restrict__ qbase = q  + ((size_t)(b * N_ + i0)) * D_;

    float acc0 = 0.f, acc1 = 0.f, acc2 = 0.f, acc3 = 0.f;

    #pragma unroll 8
    for (int d = 0; d < D_; ++d) {
        const float kv = kcol[(size_t)d * N_];
        const float q0 = qbase[d];
        const float q1 = qbase[D_ + d];
        const float q2 = qbase[2 * D_ + d];
        const float q3 = qbase[3 * D_ + d];
        acc0 += fabsf(q0 - kv);
        acc1 += fabsf(q1 - kv);
        acc2 += fabsf(q2 - kv);
        acc3 += fabsf(q3 - kv);
    }

    s_mat[0][t] = -acc0;
    s_mat[1][t] = -acc1;
    s_mat[2][t] = -acc2;
    s_mat[3][t] = -acc3;
    __syncthreads();

    // ---------------- Phase B: softmax, one wave per row ----------------
    {
        const int w = t >> 6;
        const int l = t & 63;
        float v0 = s_mat[w][l];
        float v1 = s_mat[w][l + 64];
        float v2 = s_mat[w][l + 128];
        float v3 = s_mat[w][l + 192];
        float m = fmaxf(fmaxf(v0, v1), fmaxf(v2, v3));
        #pragma unroll
        for (int off = 32; off; off >>= 1) m = fmaxf(m, __shfl_xor(m, off));
        const float c = 1.4426950408889634f;
        float e0 = exp2f((v0 - m) * c);
        float e1 = exp2f((v1 - m) * c);
        float e2 = exp2f((v2 - m) * c);
        float e3 = exp2f((v3 - m) * c);
        float s = (e0 + e1) + (e2 + e3);
        #pragma unroll
        for (int off = 32; off; off >>= 1) s += __shfl_xor(s, off);
        const float r = 1.0f / s;
        s_mat[w][l]       = e0 * r;
        s_mat[w][l + 64]  = e1 * r;
        s_mat[w][l + 128] = e2 * r;
        s_mat[w][l + 192] = e3 * r;
    }
    __syncthreads();

    // ---------------- Phase C: out = attn @ v ----------------
    const int ig = t >> 7;
    const int d0 = (t & 127) * 4;
    const float* __restrict__ vbase = v + ((size_t)b * N_) * D_ + d0;
    const float* __restrict__ wr0 = &s_mat[2 * ig][0];
    const float* __restrict__ wr1 = &s_mat[2 * ig + 1][0];

    float4 a0 = make_float4(0.f, 0.f, 0.f, 0.f);
    float4 a1 = make_float4(0.f, 0.f, 0.f, 0.f);

#define PV_STEP(W0, W1, VV)                                     \
    a0.x += (W0) * (VV).x; a0.y += (W0) * (VV).y;               \
    a0.z += (W0) * (VV).z; a0.w += (W0) * (VV).w;               \
    a1.x += (W1) * (VV).x; a1.y += (W1) * (VV).y;               \
    a1.z += (W1) * (VV).z; a1.w += (W1) * (VV).w;

    #pragma unroll 2
    for (int j = 0; j < N_; j += 4) {
        const float4 w0 = *(const float4*)(wr0 + j);
        const float4 w1 = *(const float4*)(wr1 + j);
        const float4 vv0 = *(const float4*)(vbase + (size_t)(j + 0) * D_);
        const float4 vv1 = *(const float4*)(vbase + (size_t)(j + 1) * D_);
        const float4 vv2 = *(const float4*)(vbase + (size_t)(j + 2) * D_);
        const float4 vv3 = *(const float4*)(vbase + (size_t)(j + 3) * D_);
        PV_STEP(w0.x, w1.x, vv0)
        PV_STEP(w0.y, w1.y, vv1)
        PV_STEP(w0.z, w1.z, vv2)
        PV_STEP(w0.w, w1.w, vv3)
    }
#undef PV_STEP

    float* op = out + ((size_t)(b * N_ + i0 + 2 * ig)) * D_ + d0;
    *(float4*)op        = a0;
    *(float4*)(op + D_) = a1;
}

// ---------- Fallback (round-1 kernel, used if ws too small) ----------
__global__ __launch_bounds__(256, 2)
void manh_attn_legacy(const float* __restrict__ q,
                      const float* __restrict__ k,
                      const float* __restrict__ v,
                      float* __restrict__ out)
{
    __shared__ float s_mat[TI][N_];
    const int t   = threadIdx.x;
    const int bid = blockIdx.x;
    const int b   = bid >> 6;
    const int i0  = (bid & 63) * TI;

    const float* __restrict__ krow  = k + ((size_t)(b * N_ + t)) * D_;
    const float* __restrict__ qbase = q + ((size_t)(b * N_ + i0)) * D_;

    float acc0 = 0.f, acc1 = 0.f, acc2 = 0.f, acc3 = 0.f;
    #pragma unroll 4
    for (int d = 0; d < D_; d += 4) {
        const float4 kv = *(const float4*)(krow + d);
        const float4 q0 = *(const float4*)(qbase + d);
        const float4 q1 = *(const float4*)(qbase + D_ + d);
        const float4 q2 = *(const float4*)(qbase + 2 * D_ + d);
        const float4 q3 = *(const float4*)(qbase + 3 * D_ + d);
        acc0 += (fabsf(q0.x - kv.x) + fabsf(q0.y - kv.y)) + (fabsf(q0.z - kv.z) + fabsf(q0.w - kv.w));
        acc1 += (fabsf(q1.x - kv.x) + fabsf(q1.y - kv.y)) + (fabsf(q1.z - kv.z) + fabsf(q1.w - kv.w));
        acc2 += (fabsf(q2.x - kv.x) + fabsf(q2.y - kv.y)) + (fabsf(q2.z - kv.z) + fabsf(q2.w - kv.w));
        acc3 += (fabsf(q3.x - kv.x) + fabsf(q3.y - kv.y)) + (fabsf(q3.z - kv.z) + fabsf(q3.w - kv.w));
    }
    s_mat[0][t] = -acc0; s_mat[1][t] = -acc1; s_mat[2][t] = -acc2; s_mat[3][t] = -acc3;
    __syncthreads();
    {
        const int w = t >> 6;
        const int l = t & 63;
        float v0 = s_mat[w][l], v1 = s_mat[w][l + 64], v2 = s_mat[w][l + 128], v3 = s_mat[w][l + 192];
        float m = fmaxf(fmaxf(v0, v1), fmaxf(v2, v3));
        #pragma unroll
        for (int off = 32; off; off >>= 1) m = fmaxf(m, __shfl_xor(m, off));
        const float c = 1.4426950408889634f;
        float e0 = exp2f((v0 - m) * c), e1 = exp2f((v1 - m) * c);
        float e2 = exp2f((v2 - m) * c), e3 = exp2f((v3 - m) * c);
        float s = (e0 + e1) + (e2 + e3);
        #pragma unroll
        for (int off = 32; off; off >>= 1) s += __shfl_xor(s, off);
        const float r = 1.0f / s;
        s_mat[w][l] = e0 * r; s_mat[w][l + 64] = e1 * r;
        s_mat[w][l + 128] = e2 * r; s_mat[w][l + 192] = e3 * r;
    }
    __syncthreads();
    const int ig = t >> 7;
    const int d0 = (t & 127) * 4;
    const float* __restrict__ vbase = v + ((size_t)b * N_) * D_ + d0;
    const float* __restrict__ wr0 = &s_mat[2 * ig][0];
    const float* __restrict__ wr1 = &s_mat[2 * ig + 1][0];
    float4 a0 = make_float4(0.f, 0.f, 0.f, 0.f);
    float4 a1 = make_float4(0.f, 0.f, 0.f, 0.f);
#define PV_STEP(W0, W1, VV)                                     \
    a0.x += (W0) * (VV).x; a0.y += (W0) * (VV).y;               \
    a0.z += (W0) * (VV).z; a0.w += (W0) * (VV).w;               \
    a1.x += (W1) * (VV).x; a1.y += (W1) * (VV).y;               \
    a1.z += (W1) * (VV).z; a1.w += (W1) * (VV).w;
    #pragma unroll 2
    for (int j = 0; j < N_; j += 4) {
        const float4 w0 = *(const float4*)(wr0 + j);
        const float4 w1 = *(const float4*)(wr1 + j);
        const float4 vv0 = *(const float4*)(vbase + (size_t)(j + 0) * D_);
        const float4 vv1 = *(const float4*)(vbase + (size_t)(j + 1) * D_);
        const float4 vv2 = *(const float4*)(vbase + (size_t)(j + 2) * D_);
        const float4 vv3 = *(const float4*)(vbase + (size_t)(j + 3) * D_);
        PV_STEP(w0.x, w1.x, vv0)
        PV_STEP(w0.y, w1.y, vv1)
        PV_STEP(w0.z, w1.z, vv2)
        PV_STEP(w0.w, w1.w, vv3)
    }
#undef PV_STEP
    float* op = out + ((size_t)(b * N_ + i0 + 2 * ig)) * D_ + d0;
    *(float4*)op        = a0;
    *(float4*)(op + D_) = a1;
}

extern "C" void kernel_launch(void* const* d_in, const int* in_sizes, int n_in,
                              void* d_out, int out_size, void* d_ws, size_t ws_size,
                              hipStream_t stream)
{
    const float* q = (const float*)d_in[0];
    const float* k = (const float*)d_in[1];
    const float* v = (const float*)d_in[2];
    float* out = (float*)d_out;

    const size_t kT_bytes = (size_t)B_ * N_ * D_ * sizeof(float);
    if (ws_size >= kT_bytes) {
        float* kT = (float*)d_ws;
        transpose_k<<<dim3(D_ / 32, N_ / 32, B_), dim3(32, 8), 0, stream>>>(k, kT);
        manh_attn_kernel<<<dim3(B_ * (N_ / TI)), dim3(256), 0, stream>>>(q, kT, v, out);
    } else {
        manh_attn_legacy<<<dim3(B_ * (N_ / TI)), dim3(256), 0, stream>>>(q, k, v, out);
    }
}